// Round 1
// baseline (639.623 us; speedup 1.0000x reference)
//
#include <hip/hip_runtime.h>
#include <math.h>

// ---------------------------------------------------------------------------
// GCN regressor: 3x GCNConv (pull-based CSR aggregation) + mean-pool + MLP.
// All fp32. CSR built per call (deterministic within fp tolerance).
// ---------------------------------------------------------------------------

__global__ void count_deg_kernel(const int* __restrict__ dst, int* __restrict__ deg, int E) {
    int e = blockIdx.x * blockDim.x + threadIdx.x;
    if (e < E) atomicAdd(&deg[dst[e]], 1);
}

__global__ void invsqrt_kernel(const int* __restrict__ deg, float* __restrict__ isq, int n) {
    int i = blockIdx.x * blockDim.x + threadIdx.x;
    if (i < n) isq[i] = rsqrtf((float)(deg[i] + 1));   // +1 self-loop
}

__global__ void scan_block_kernel(const int* __restrict__ deg, int* __restrict__ row_start,
                                  int* __restrict__ bsum, int n) {
    __shared__ int s[1024];
    int t = threadIdx.x;
    int i = blockIdx.x * 1024 + t;
    int v = (i < n) ? deg[i] : 0;
    s[t] = v;
    __syncthreads();
    for (int off = 1; off < 1024; off <<= 1) {
        int x = 0;
        if (t >= off) x = s[t - off];
        __syncthreads();
        s[t] += x;
        __syncthreads();
    }
    if (i < n) row_start[i + 1] = s[t];
    if (t == 1023) bsum[blockIdx.x] = s[1023];
    if (blockIdx.x == 0 && t == 0) row_start[0] = 0;
}

__global__ void scan_bsum_kernel(int* bsum, int nb) {
    if (blockIdx.x == 0 && threadIdx.x == 0) {
        int run = 0;
        for (int b = 0; b < nb; ++b) { int t = bsum[b]; bsum[b] = run; run += t; }
    }
}

__global__ void add_offset_kernel(int* __restrict__ row_start, const int* __restrict__ bsum, int n) {
    int i = blockIdx.x * 1024 + threadIdx.x;
    if (i < n) row_start[i + 1] += bsum[blockIdx.x];
}

__global__ void fill_csr_kernel(const int* __restrict__ src, const int* __restrict__ dst,
                                int* __restrict__ cursor, const int* __restrict__ row_start,
                                int* __restrict__ colx, int E) {
    int e = blockIdx.x * blockDim.x + threadIdx.x;
    if (e < E) {
        int d = dst[e];
        int pos = atomicAdd(&cursor[d], 1);
        colx[row_start[d] + pos] = src[e];
    }
}

// Pull aggregation: out[r] = sum_{s in N(r)} feat[s]*isq[s]*isq[r] + feat[r]/deg[r] (+bias, act)
// One wave per row; lane covers VEC consecutive features. F = VEC*64.
template <int VEC>
__global__ __launch_bounds__(256) void agg_kernel(const float* __restrict__ feat,
                                                  float* __restrict__ out,
                                                  const int* __restrict__ row_start,
                                                  const int* __restrict__ colx,
                                                  const float* __restrict__ isq,
                                                  const float* __restrict__ bias,
                                                  int n, int act) {
    const int F = VEC * 64;
    int wid = blockIdx.x * (blockDim.x >> 6) + (threadIdx.x >> 6);
    if (wid >= n) return;
    int lane = threadIdx.x & 63;
    float isd = isq[wid];
    float acc[VEC];
    const float* selfrow = feat + (size_t)wid * F + lane * VEC;
    float w0 = isd * isd;
    if constexpr (VEC == 4) {
        float4 v = *(const float4*)selfrow;
        acc[0] = v.x * w0; acc[1] = v.y * w0; acc[2] = v.z * w0; acc[3] = v.w * w0;
    } else {
        float2 v = *(const float2*)selfrow;
        acc[0] = v.x * w0; acc[1] = v.y * w0;
    }
    int beg = row_start[wid], end = row_start[wid + 1];
    for (int j = beg; j < end; ++j) {
        int s = colx[j];
        float w = isq[s] * isd;
        const float* p = feat + (size_t)s * F + lane * VEC;
        if constexpr (VEC == 4) {
            float4 v = *(const float4*)p;
            acc[0] += v.x * w; acc[1] += v.y * w; acc[2] += v.z * w; acc[3] += v.w * w;
        } else {
            float2 v = *(const float2*)p;
            acc[0] += v.x * w; acc[1] += v.y * w;
        }
    }
    if (bias) {
#pragma unroll
        for (int k = 0; k < VEC; ++k) acc[k] += bias[lane * VEC + k];
    }
    if (act) {
#pragma unroll
        for (int k = 0; k < VEC; ++k) acc[k] = tanhf(acc[k]);
    }
    float* o = out + (size_t)wid * F + lane * VEC;
    if constexpr (VEC == 4) { float4 v = {acc[0], acc[1], acc[2], acc[3]}; *(float4*)o = v; }
    else                    { float2 v = {acc[0], acc[1]}; *(float2*)o = v; }
}

// fp32 GEMM: C[M,Nout] = A[M,K] @ B[K,Nout] (+bias, optional tanh).
// 64x64 tile, BK=16, 256 threads, 4x4 micro-tile. Nout % 64 == 0, K % 16 == 0.
#define BM 64
#define BN 64
#define BK 16
__global__ __launch_bounds__(256) void sgemm_kernel(const float* __restrict__ A,
                                                    const float* __restrict__ B,
                                                    float* __restrict__ C,
                                                    const float* __restrict__ bias,
                                                    int M, int K, int Nout, int act) {
    __shared__ float As[BK][BM + 4];
    __shared__ float Bs[BK][BN + 4];
    int t = threadIdx.x;
    int tx = t & 15, ty = t >> 4;
    int row0 = blockIdx.y * BM, col0 = blockIdx.x * BN;

    int am = t >> 2, ak = (t & 3) * 4;    // A tile load coords (64 rows x 16 k)
    int bk = t >> 4, bn = (t & 15) * 4;   // B tile load coords (16 k x 64 cols)

    float acc[4][4] = {{0.f}};

    for (int k0 = 0; k0 < K; k0 += BK) {
        float4 av = {0.f, 0.f, 0.f, 0.f};
        int arow = row0 + am;
        if (arow < M) av = *(const float4*)(A + (size_t)arow * K + k0 + ak);
        As[ak + 0][am] = av.x;
        As[ak + 1][am] = av.y;
        As[ak + 2][am] = av.z;
        As[ak + 3][am] = av.w;
        float4 bv = *(const float4*)(B + (size_t)(k0 + bk) * Nout + col0 + bn);
        *(float4*)&Bs[bk][bn] = bv;
        __syncthreads();
#pragma unroll
        for (int kk = 0; kk < BK; ++kk) {
            float4 a = *(const float4*)&As[kk][ty * 4];
            float4 b = *(const float4*)&Bs[kk][tx * 4];
            float a4[4] = {a.x, a.y, a.z, a.w};
            float b4[4] = {b.x, b.y, b.z, b.w};
#pragma unroll
            for (int i = 0; i < 4; ++i)
#pragma unroll
                for (int j = 0; j < 4; ++j) acc[i][j] += a4[i] * b4[j];
        }
        __syncthreads();
    }

#pragma unroll
    for (int i = 0; i < 4; ++i) {
        int row = row0 + ty * 4 + i;
        if (row < M) {
            float o[4];
#pragma unroll
            for (int j = 0; j < 4; ++j) {
                float v = acc[i][j];
                if (bias) v += bias[col0 + tx * 4 + j];
                if (act) v = tanhf(v);
                o[j] = v;
            }
            float4 ov = {o[0], o[1], o[2], o[3]};
            *(float4*)(C + (size_t)row * Nout + col0 + tx * 4) = ov;
        }
    }
}

__global__ void gstart_kernel(const int* __restrict__ batch, int* __restrict__ gstart,
                              int n, int G) {
    int g = blockIdx.x * blockDim.x + threadIdx.x;
    if (g <= G) {
        int lo = 0, hi = n;
        while (lo < hi) {
            int mid = (lo + hi) >> 1;
            if (batch[mid] < g) lo = mid + 1; else hi = mid;
        }
        gstart[g] = lo;
    }
}

// One block (128 threads) per graph: mean-pool h3 [N,128] + x_global column.
__global__ __launch_bounds__(128) void pool_kernel(const float* __restrict__ h3,
                                                   const int* __restrict__ gstart,
                                                   const float* __restrict__ na,
                                                   const float* __restrict__ nb,
                                                   const float* __restrict__ mw,
                                                   float* __restrict__ pooled, int G) {
    int g = blockIdx.x, t = threadIdx.x;
    int beg = gstart[g], end = gstart[g + 1];
    float s = 0.f;
    for (int i = beg; i < end; ++i) s += h3[(size_t)i * 128 + t];
    float cnt = (float)(end - beg);
    float inv = 1.f / fmaxf(cnt, 1.f);
    pooled[(size_t)g * 129 + t] = s * inv;
    if (t == 0)
        pooled[(size_t)g * 129 + 128] = (end > beg) ? (na[g] + nb[g] + mw[g]) * (1.f / 3.f) : 0.f;
}

// One block (128 threads) per graph: 129->128->64->32->1 MLP with ReLU.
__global__ __launch_bounds__(128) void mlp_kernel(const float* __restrict__ pooled,
                                                  const float* __restrict__ fW1, const float* __restrict__ fb1,
                                                  const float* __restrict__ fW2, const float* __restrict__ fb2,
                                                  const float* __restrict__ fW3, const float* __restrict__ fb3,
                                                  const float* __restrict__ fW4, const float* __restrict__ fb4,
                                                  float* __restrict__ out, int G) {
    __shared__ float p[129];
    __shared__ float o1[128];
    __shared__ float o2[64];
    __shared__ float o3[32];
    int g = blockIdx.x, t = threadIdx.x;
    for (int i = t; i < 129; i += 128) p[i] = pooled[(size_t)g * 129 + i];
    __syncthreads();
    {
        float a = fb1[t];
        for (int i = 0; i < 129; ++i) a += p[i] * fW1[i * 128 + t];
        o1[t] = fmaxf(a, 0.f);
    }
    __syncthreads();
    if (t < 64) {
        float a = fb2[t];
        for (int i = 0; i < 128; ++i) a += o1[i] * fW2[i * 64 + t];
        o2[t] = fmaxf(a, 0.f);
    }
    __syncthreads();
    if (t < 32) {
        float a = fb3[t];
        for (int i = 0; i < 64; ++i) a += o2[i] * fW3[i * 32 + t];
        o3[t] = fmaxf(a, 0.f);
    }
    __syncthreads();
    if (t == 0) {
        float a = fb4[0];
        for (int i = 0; i < 32; ++i) a += o3[i] * fW4[i];
        out[g] = a;
    }
}

extern "C" void kernel_launch(void* const* d_in, const int* in_sizes, int n_in,
                              void* d_out, int out_size, void* d_ws, size_t ws_size,
                              hipStream_t stream) {
    const float* x     = (const float*)d_in[0];
    const int*   ei    = (const int*)d_in[1];
    const int*   batch = (const int*)d_in[2];
    const float* na    = (const float*)d_in[3];
    const float* nbonds= (const float*)d_in[4];
    const float* mw    = (const float*)d_in[5];
    const float* W1 = (const float*)d_in[6];  const float* b1 = (const float*)d_in[7];
    const float* W2 = (const float*)d_in[8];  const float* b2 = (const float*)d_in[9];
    const float* W3 = (const float*)d_in[10]; const float* b3 = (const float*)d_in[11];
    const float* fW1 = (const float*)d_in[12]; const float* fb1 = (const float*)d_in[13];
    const float* fW2 = (const float*)d_in[14]; const float* fb2 = (const float*)d_in[15];
    const float* fW3 = (const float*)d_in[16]; const float* fb3 = (const float*)d_in[17];
    const float* fW4 = (const float*)d_in[18]; const float* fb4 = (const float*)d_in[19];
    float* out = (float*)d_out;

    const int N = in_sizes[2];          // 50000
    const int E = in_sizes[1] / 2;      // 800000
    const int F = in_sizes[0] / N;      // 128
    const int H = in_sizes[7];          // 256
    const int G = in_sizes[3];          // 1024

    const int* src = ei;
    const int* dst = ei + E;

    // ---- workspace carve-up ----
    char* w = (char*)d_ws;
    size_t off = 0;
    auto take = [&](size_t bytes) -> void* {
        void* p = w + off;
        off += (bytes + 255) & ~(size_t)255;
        return p;
    };
    int*   deg       = (int*)take((size_t)N * 4);
    int*   cursor    = (int*)take((size_t)N * 4);
    int*   row_start = (int*)take((size_t)(N + 1) * 4);
    int*   bsum      = (int*)take(256 * 4);
    int*   colx      = (int*)take((size_t)E * 4);
    float* isq       = (float*)take((size_t)N * 4);
    int*   gstart    = (int*)take((size_t)(G + 1) * 4);
    float* S0        = (float*)take((size_t)N * H * 4);
    float* S1        = (float*)take((size_t)N * H * 4);
    float* S2        = (float*)take((size_t)N * H * 4);
    float* pooled    = (float*)take((size_t)G * (F + 1) * 4);
    (void)ws_size; (void)n_in; (void)out_size;

    hipMemsetAsync(deg, 0, (size_t)N * 4, stream);
    hipMemsetAsync(cursor, 0, (size_t)N * 4, stream);

    const int nb = (N + 1023) / 1024;

    count_deg_kernel<<<(E + 255) / 256, 256, 0, stream>>>(dst, deg, E);
    invsqrt_kernel<<<(N + 255) / 256, 256, 0, stream>>>(deg, isq, N);
    scan_block_kernel<<<nb, 1024, 0, stream>>>(deg, row_start, bsum, N);
    scan_bsum_kernel<<<1, 64, 0, stream>>>(bsum, nb);
    add_offset_kernel<<<nb, 1024, 0, stream>>>(row_start, bsum, N);
    fill_csr_kernel<<<(E + 255) / 256, 256, 0, stream>>>(src, dst, cursor, row_start, colx, E);

    const int waves_per_blk = 4;                       // 256 threads
    const int agg_grid = (N + waves_per_blk - 1) / waves_per_blk;

    // conv1: aggregate x first (F=128), then GEMM (+b1, tanh)
    agg_kernel<2><<<agg_grid, 256, 0, stream>>>(x, S0, row_start, colx, isq, nullptr, N, 0);
    {
        dim3 grid(H / 64, (N + 63) / 64);
        sgemm_kernel<<<grid, 256, 0, stream>>>(S0, W1, S1, b1, N, F, H, 1);   // h1 in S1
    }
    // conv2: GEMM then aggregate (+b2, tanh)
    {
        dim3 grid(H / 64, (N + 63) / 64);
        sgemm_kernel<<<grid, 256, 0, stream>>>(S1, W2, S2, nullptr, N, H, H, 0); // t2 in S2
    }
    agg_kernel<4><<<agg_grid, 256, 0, stream>>>(S2, S0, row_start, colx, isq, b2, N, 1); // h2 in S0
    // conv3: GEMM then aggregate (+b3)
    {
        dim3 grid(F / 64, (N + 63) / 64);
        sgemm_kernel<<<grid, 256, 0, stream>>>(S0, W3, S1, nullptr, N, H, F, 0); // t3 in S1
    }
    agg_kernel<2><<<agg_grid, 256, 0, stream>>>(S1, S2, row_start, colx, isq, b3, N, 0); // h3 in S2

    // pooling + MLP head
    gstart_kernel<<<(G + 1 + 255) / 256, 256, 0, stream>>>(batch, gstart, N, G);
    pool_kernel<<<G, 128, 0, stream>>>(S2, gstart, na, nbonds, mw, pooled, G);
    mlp_kernel<<<G, 128, 0, stream>>>(pooled, fW1, fb1, fW2, fb2, fW3, fb3, fW4, fb4, out, G);
}

// Round 2
// 360.323 us; speedup vs baseline: 1.7751x; 1.7751x over previous
//
#include <hip/hip_runtime.h>
#include <math.h>

// ---------------------------------------------------------------------------
// GCN regressor, round 2: fp16 node-feature trunk.
//   - CSR build (count/scan/fill) as round 1.
//   - Aggregation: pull-based, fp16 gather, fp32 accumulate, x4 unroll.
//   - GEMMs: MFMA f16 (16x16x32), 128x128 tile, BK=64, global_load_lds staging.
//   - Pool + MLP head in fp32.
// ---------------------------------------------------------------------------

typedef _Float16 v8h __attribute__((ext_vector_type(8)));
typedef _Float16 v4h __attribute__((ext_vector_type(4)));
typedef _Float16 v2h __attribute__((ext_vector_type(2)));
typedef float    v4f __attribute__((ext_vector_type(4)));

#define GLOAD_LDS16(g, l)                                                      \
    __builtin_amdgcn_global_load_lds(                                          \
        (const __attribute__((address_space(1))) void*)(g),                    \
        (__attribute__((address_space(3))) void*)(l), 16, 0, 0)

// ---------------- CSR build ----------------
__global__ void count_deg_kernel(const int* __restrict__ dst, int* __restrict__ deg, int E) {
    int e = blockIdx.x * blockDim.x + threadIdx.x;
    if (e < E) atomicAdd(&deg[dst[e]], 1);
}

__global__ void invsqrt_kernel(const int* __restrict__ deg, float* __restrict__ isq, int n) {
    int i = blockIdx.x * blockDim.x + threadIdx.x;
    if (i < n) isq[i] = rsqrtf((float)(deg[i] + 1));   // +1 self-loop
}

__global__ void scan_block_kernel(const int* __restrict__ deg, int* __restrict__ row_start,
                                  int* __restrict__ bsum, int n) {
    __shared__ int s[1024];
    int t = threadIdx.x;
    int i = blockIdx.x * 1024 + t;
    int v = (i < n) ? deg[i] : 0;
    s[t] = v;
    __syncthreads();
    for (int off = 1; off < 1024; off <<= 1) {
        int x = 0;
        if (t >= off) x = s[t - off];
        __syncthreads();
        s[t] += x;
        __syncthreads();
    }
    if (i < n) row_start[i + 1] = s[t];
    if (t == 1023) bsum[blockIdx.x] = s[1023];
    if (blockIdx.x == 0 && t == 0) row_start[0] = 0;
}

__global__ void scan_bsum_kernel(int* bsum, int nb) {
    if (blockIdx.x == 0 && threadIdx.x == 0) {
        int run = 0;
        for (int b = 0; b < nb; ++b) { int t = bsum[b]; bsum[b] = run; run += t; }
    }
}

__global__ void add_offset_kernel(int* __restrict__ row_start, const int* __restrict__ bsum, int n) {
    int i = blockIdx.x * 1024 + threadIdx.x;
    if (i < n) row_start[i + 1] += bsum[blockIdx.x];
}

__global__ void fill_csr_kernel(const int* __restrict__ src, const int* __restrict__ dst,
                                int* __restrict__ cursor, const int* __restrict__ row_start,
                                int* __restrict__ colx, int E) {
    int e = blockIdx.x * blockDim.x + threadIdx.x;
    if (e < E) {
        int d = dst[e];
        int pos = atomicAdd(&cursor[d], 1);
        colx[row_start[d] + pos] = src[e];
    }
}

// ---------------- casts ----------------
__global__ void cast16_kernel(const float* __restrict__ in, _Float16* __restrict__ out, int n4) {
    int i = blockIdx.x * blockDim.x + threadIdx.x;
    if (i < n4) {
        float4 v = *(const float4*)(in + (size_t)i * 4);
        v4h o = {(_Float16)v.x, (_Float16)v.y, (_Float16)v.z, (_Float16)v.w};
        *(v4h*)(out + (size_t)i * 4) = o;
    }
}

// Wt[n][k] = (f16) W[k][n]
__global__ void wcast_t_kernel(const float* __restrict__ W, _Float16* __restrict__ Wt,
                               int K, int N) {
    int i = blockIdx.x * blockDim.x + threadIdx.x;
    if (i < K * N) {
        int k = i / N, n = i % N;
        Wt[(size_t)n * K + k] = (_Float16)W[i];
    }
}

// ---------------- aggregation (pull, fp16 feat, fp32 accum) ----------------
// out[r] = sum_{s in N(r)} feat[s]*isq[s]*isq[r] + feat[r]*isq[r]^2  (+bias, tanh)
// One wave per row; lane covers VEC consecutive features. F = VEC*64.
template <int VEC, bool OUTF32, bool DOTANH>
__global__ __launch_bounds__(256) void agg16_kernel(const _Float16* __restrict__ feat,
                                                    void* __restrict__ outp,
                                                    const int* __restrict__ row_start,
                                                    const int* __restrict__ colx,
                                                    const float* __restrict__ isq,
                                                    const float* __restrict__ bias,
                                                    int n) {
    const int F = VEC * 64;
    int wid = blockIdx.x * 4 + (threadIdx.x >> 6);
    if (wid >= n) return;
    int lane = threadIdx.x & 63;
    float isd = isq[wid];
    float acc[VEC];
    {
        float w0 = isd * isd;
        const _Float16* p = feat + (size_t)wid * F + lane * VEC;
        if constexpr (VEC == 4) {
            v4h v = *(const v4h*)p;
#pragma unroll
            for (int k = 0; k < 4; ++k) acc[k] = (float)v[k] * w0;
        } else {
            v2h v = *(const v2h*)p;
            acc[0] = (float)v[0] * w0;
            acc[1] = (float)v[1] * w0;
        }
    }
    int beg = row_start[wid], end = row_start[wid + 1];
    int j = beg;
    for (; j + 4 <= end; j += 4) {
        int s0 = colx[j + 0], s1 = colx[j + 1], s2 = colx[j + 2], s3 = colx[j + 3];
        float w0 = isq[s0] * isd, w1 = isq[s1] * isd, w2 = isq[s2] * isd, w3 = isq[s3] * isd;
        if constexpr (VEC == 4) {
            v4h a = *(const v4h*)(feat + (size_t)s0 * F + lane * 4);
            v4h b = *(const v4h*)(feat + (size_t)s1 * F + lane * 4);
            v4h c = *(const v4h*)(feat + (size_t)s2 * F + lane * 4);
            v4h d = *(const v4h*)(feat + (size_t)s3 * F + lane * 4);
#pragma unroll
            for (int k = 0; k < 4; ++k)
                acc[k] += (float)a[k] * w0 + (float)b[k] * w1 + (float)c[k] * w2 + (float)d[k] * w3;
        } else {
            v2h a = *(const v2h*)(feat + (size_t)s0 * F + lane * 2);
            v2h b = *(const v2h*)(feat + (size_t)s1 * F + lane * 2);
            v2h c = *(const v2h*)(feat + (size_t)s2 * F + lane * 2);
            v2h d = *(const v2h*)(feat + (size_t)s3 * F + lane * 2);
#pragma unroll
            for (int k = 0; k < 2; ++k)
                acc[k] += (float)a[k] * w0 + (float)b[k] * w1 + (float)c[k] * w2 + (float)d[k] * w3;
        }
    }
    for (; j < end; ++j) {
        int s = colx[j];
        float w = isq[s] * isd;
        const _Float16* p = feat + (size_t)s * F + lane * VEC;
        if constexpr (VEC == 4) {
            v4h v = *(const v4h*)p;
#pragma unroll
            for (int k = 0; k < 4; ++k) acc[k] += (float)v[k] * w;
        } else {
            v2h v = *(const v2h*)p;
            acc[0] += (float)v[0] * w;
            acc[1] += (float)v[1] * w;
        }
    }
    if (bias) {
#pragma unroll
        for (int k = 0; k < VEC; ++k) acc[k] += bias[lane * VEC + k];
    }
    if constexpr (DOTANH) {
#pragma unroll
        for (int k = 0; k < VEC; ++k) acc[k] = tanhf(acc[k]);
    }
    if constexpr (OUTF32) {
        float* o = (float*)outp + (size_t)wid * F + lane * VEC;
        if constexpr (VEC == 4) { float4 v = {acc[0], acc[1], acc[2], acc[3]}; *(float4*)o = v; }
        else                    { float2 v = {acc[0], acc[1]}; *(float2*)o = v; }
    } else {
        _Float16* o = (_Float16*)outp + (size_t)wid * F + lane * VEC;
        if constexpr (VEC == 4) {
            v4h v = {(_Float16)acc[0], (_Float16)acc[1], (_Float16)acc[2], (_Float16)acc[3]};
            *(v4h*)o = v;
        } else {
            v2h v = {(_Float16)acc[0], (_Float16)acc[1]};
            *(v2h*)o = v;
        }
    }
}

// ---------------- MFMA f16 GEMM ----------------
// C[M,Nout] = act(A[Mpad,K] @ B[K,Nout] + bias), B given transposed Bt[Nout,K].
// 128x128 tile, BK=64, 256 threads = 4 waves (2x2), each wave 64x64 (4x4 frags).
// Mpad % 128 == 0 (pad rows computed, stored to pad region of C).
__global__ __launch_bounds__(256) void gemm16_kernel(const _Float16* __restrict__ A,
                                                     const _Float16* __restrict__ Bt,
                                                     _Float16* __restrict__ C,
                                                     const float* __restrict__ bias,
                                                     int K, int Nout, int act) {
    __shared__ _Float16 As[128 * 64];
    __shared__ _Float16 Bs[128 * 64];
    const int tid = threadIdx.x;
    const int lane = tid & 63;
    const int wid = tid >> 6;
    const int wr = wid >> 1, wc = wid & 1;     // wave 64x64 sub-tile
    const int row0 = blockIdx.y * 128, col0 = blockIdx.x * 128;

    v4f acc[4][4];
#pragma unroll
    for (int m = 0; m < 4; ++m)
#pragma unroll
        for (int n = 0; n < 4; ++n) acc[m][n] = (v4f){0.f, 0.f, 0.f, 0.f};

    for (int k0 = 0; k0 < K; k0 += 64) {
        // stage A tile: 128 rows x 64 k, linear LDS, 4 calls x 256 thr x 16B
#pragma unroll
        for (int c = 0; c < 4; ++c) {
            int l = c * 2048 + tid * 8;              // half index
            int row = l >> 6, kh = l & 63;
            GLOAD_LDS16(A + (size_t)(row0 + row) * K + k0 + kh, As + l);
        }
        // stage Bt tile: 128 cols x 64 k
#pragma unroll
        for (int c = 0; c < 4; ++c) {
            int l = c * 2048 + tid * 8;
            int cc = l >> 6, kh = l & 63;
            GLOAD_LDS16(Bt + (size_t)(col0 + cc) * K + k0 + kh, Bs + l);
        }
        __syncthreads();
#pragma unroll
        for (int kk = 0; kk < 2; ++kk) {
            v8h af[4], bf[4];
            const int khb = kk * 32 + (lane >> 4) * 8;
#pragma unroll
            for (int m = 0; m < 4; ++m) {
                int row = wr * 64 + m * 16 + (lane & 15);
                af[m] = *(const v8h*)&As[row * 64 + khb];
            }
#pragma unroll
            for (int n = 0; n < 4; ++n) {
                int col = wc * 64 + n * 16 + (lane & 15);
                bf[n] = *(const v8h*)&Bs[col * 64 + khb];
            }
#pragma unroll
            for (int m = 0; m < 4; ++m)
#pragma unroll
                for (int n = 0; n < 4; ++n)
                    acc[m][n] = __builtin_amdgcn_mfma_f32_16x16x32_f16(af[m], bf[n], acc[m][n], 0, 0, 0);
        }
        __syncthreads();
    }

    // epilogue: D row=(lane>>4)*4+r, col=lane&15 within each 16x16 fragment
#pragma unroll
    for (int m = 0; m < 4; ++m) {
#pragma unroll
        for (int n = 0; n < 4; ++n) {
            int col = col0 + wc * 64 + n * 16 + (lane & 15);
            float bv = bias ? bias[col] : 0.f;
#pragma unroll
            for (int r = 0; r < 4; ++r) {
                int row = row0 + wr * 64 + m * 16 + (lane >> 4) * 4 + r;
                float v = acc[m][n][r] + bv;
                if (act) v = tanhf(v);
                C[(size_t)row * Nout + col] = (_Float16)v;
            }
        }
    }
}

// ---------------- pooling + MLP head ----------------
__global__ void gstart_kernel(const int* __restrict__ batch, int* __restrict__ gstart,
                              int n, int G) {
    int g = blockIdx.x * blockDim.x + threadIdx.x;
    if (g <= G) {
        int lo = 0, hi = n;
        while (lo < hi) {
            int mid = (lo + hi) >> 1;
            if (batch[mid] < g) lo = mid + 1; else hi = mid;
        }
        gstart[g] = lo;
    }
}

__global__ __launch_bounds__(128) void pool_kernel(const float* __restrict__ h3,
                                                   const int* __restrict__ gstart,
                                                   const float* __restrict__ na,
                                                   const float* __restrict__ nb,
                                                   const float* __restrict__ mw,
                                                   float* __restrict__ pooled, int G) {
    int g = blockIdx.x, t = threadIdx.x;
    int beg = gstart[g], end = gstart[g + 1];
    float s = 0.f;
    for (int i = beg; i < end; ++i) s += h3[(size_t)i * 128 + t];
    float cnt = (float)(end - beg);
    float inv = 1.f / fmaxf(cnt, 1.f);
    pooled[(size_t)g * 129 + t] = s * inv;
    if (t == 0)
        pooled[(size_t)g * 129 + 128] = (end > beg) ? (na[g] + nb[g] + mw[g]) * (1.f / 3.f) : 0.f;
}

__global__ __launch_bounds__(128) void mlp_kernel(const float* __restrict__ pooled,
                                                  const float* __restrict__ fW1, const float* __restrict__ fb1,
                                                  const float* __restrict__ fW2, const float* __restrict__ fb2,
                                                  const float* __restrict__ fW3, const float* __restrict__ fb3,
                                                  const float* __restrict__ fW4, const float* __restrict__ fb4,
                                                  float* __restrict__ out, int G) {
    __shared__ float p[129];
    __shared__ float o1[128];
    __shared__ float o2[64];
    __shared__ float o3[32];
    int g = blockIdx.x, t = threadIdx.x;
    for (int i = t; i < 129; i += 128) p[i] = pooled[(size_t)g * 129 + i];
    __syncthreads();
    {
        float a = fb1[t];
        for (int i = 0; i < 129; ++i) a += p[i] * fW1[i * 128 + t];
        o1[t] = fmaxf(a, 0.f);
    }
    __syncthreads();
    if (t < 64) {
        float a = fb2[t];
        for (int i = 0; i < 128; ++i) a += o1[i] * fW2[i * 64 + t];
        o2[t] = fmaxf(a, 0.f);
    }
    __syncthreads();
    if (t < 32) {
        float a = fb3[t];
        for (int i = 0; i < 64; ++i) a += o2[i] * fW3[i * 32 + t];
        o3[t] = fmaxf(a, 0.f);
    }
    __syncthreads();
    if (t == 0) {
        float a = fb4[0];
        for (int i = 0; i < 32; ++i) a += o3[i] * fW4[i];
        out[g] = a;
    }
}

// ---------------------------------------------------------------------------
extern "C" void kernel_launch(void* const* d_in, const int* in_sizes, int n_in,
                              void* d_out, int out_size, void* d_ws, size_t ws_size,
                              hipStream_t stream) {
    const float* x     = (const float*)d_in[0];
    const int*   ei    = (const int*)d_in[1];
    const int*   batch = (const int*)d_in[2];
    const float* na    = (const float*)d_in[3];
    const float* nbonds= (const float*)d_in[4];
    const float* mw    = (const float*)d_in[5];
    const float* W1 = (const float*)d_in[6];  const float* b1 = (const float*)d_in[7];
    const float* W2 = (const float*)d_in[8];  const float* b2 = (const float*)d_in[9];
    const float* W3 = (const float*)d_in[10]; const float* b3 = (const float*)d_in[11];
    const float* fW1 = (const float*)d_in[12]; const float* fb1 = (const float*)d_in[13];
    const float* fW2 = (const float*)d_in[14]; const float* fb2 = (const float*)d_in[15];
    const float* fW3 = (const float*)d_in[16]; const float* fb3 = (const float*)d_in[17];
    const float* fW4 = (const float*)d_in[18]; const float* fb4 = (const float*)d_in[19];
    float* out = (float*)d_out;

    const int N = in_sizes[2];          // 50000
    const int E = in_sizes[1] / 2;      // 800000
    const int F = in_sizes[0] / N;      // 128
    const int H = in_sizes[7];          // 256
    const int G = in_sizes[3];          // 1024
    const int Npad = ((N + 127) / 128) * 128;   // 50048

    const int* src = ei;
    const int* dst = ei + E;

    // ---- workspace carve-up ----
    char* w = (char*)d_ws;
    size_t off = 0;
    auto take = [&](size_t bytes) -> void* {
        void* p = w + off;
        off += (bytes + 255) & ~(size_t)255;
        return p;
    };
    int*      deg       = (int*)take((size_t)N * 4);
    int*      cursor    = (int*)take((size_t)N * 4);
    int*      row_start = (int*)take((size_t)(N + 1) * 4);
    int*      bsum      = (int*)take(256 * 4);
    int*      colx      = (int*)take((size_t)E * 4);
    float*    isq       = (float*)take((size_t)N * 4);
    int*      gstart    = (int*)take((size_t)(G + 1) * 4);
    _Float16* X16       = (_Float16*)take((size_t)Npad * F * 2);
    _Float16* A0        = (_Float16*)take((size_t)Npad * F * 2);
    _Float16* H1        = (_Float16*)take((size_t)Npad * H * 2);
    _Float16* T2        = (_Float16*)take((size_t)Npad * H * 2);
    _Float16* H2        = (_Float16*)take((size_t)Npad * H * 2);
    _Float16* T3        = (_Float16*)take((size_t)Npad * F * 2);
    float*    H3        = (float*)take((size_t)Npad * F * 4);
    float*    pooled    = (float*)take((size_t)G * (F + 1) * 4);
    _Float16* Wt1       = (_Float16*)take((size_t)F * H * 2);
    _Float16* Wt2       = (_Float16*)take((size_t)H * H * 2);
    _Float16* Wt3       = (_Float16*)take((size_t)H * F * 2);
    (void)ws_size; (void)n_in; (void)out_size;

    hipMemsetAsync(deg, 0, (size_t)N * 4, stream);
    hipMemsetAsync(cursor, 0, (size_t)N * 4, stream);

    const int nb = (N + 1023) / 1024;

    count_deg_kernel<<<(E + 255) / 256, 256, 0, stream>>>(dst, deg, E);
    invsqrt_kernel<<<(N + 255) / 256, 256, 0, stream>>>(deg, isq, N);
    scan_block_kernel<<<nb, 1024, 0, stream>>>(deg, row_start, bsum, N);
    scan_bsum_kernel<<<1, 64, 0, stream>>>(bsum, nb);
    add_offset_kernel<<<nb, 1024, 0, stream>>>(row_start, bsum, N);
    fill_csr_kernel<<<(E + 255) / 256, 256, 0, stream>>>(src, dst, cursor, row_start, colx, E);

    // casts
    cast16_kernel<<<((N * F / 4) + 255) / 256, 256, 0, stream>>>(x, X16, N * F / 4);
    wcast_t_kernel<<<((F * H) + 255) / 256, 256, 0, stream>>>(W1, Wt1, F, H);
    wcast_t_kernel<<<((H * H) + 255) / 256, 256, 0, stream>>>(W2, Wt2, H, H);
    wcast_t_kernel<<<((H * F) + 255) / 256, 256, 0, stream>>>(W3, Wt3, H, F);

    const int agg_grid = (N + 3) / 4;

    // conv1: aggregate x first (F=128), then GEMM (+b1, tanh)
    agg16_kernel<2, false, false><<<agg_grid, 256, 0, stream>>>(X16, A0, row_start, colx, isq, nullptr, N);
    {
        dim3 grid(H / 128, Npad / 128);
        gemm16_kernel<<<grid, 256, 0, stream>>>(A0, Wt1, H1, b1, F, H, 1);
    }
    // conv2: GEMM then aggregate (+b2, tanh)
    {
        dim3 grid(H / 128, Npad / 128);
        gemm16_kernel<<<grid, 256, 0, stream>>>(H1, Wt2, T2, nullptr, H, H, 0);
    }
    agg16_kernel<4, false, true><<<agg_grid, 256, 0, stream>>>(T2, H2, row_start, colx, isq, b2, N);
    // conv3: GEMM then aggregate (+b3), fp32 out
    {
        dim3 grid(F / 128, Npad / 128);
        gemm16_kernel<<<grid, 256, 0, stream>>>(H2, Wt3, T3, nullptr, H, F, 0);
    }
    agg16_kernel<2, true, false><<<agg_grid, 256, 0, stream>>>(T3, H3, row_start, colx, isq, b3, N);

    // pooling + MLP head
    gstart_kernel<<<(G + 1 + 255) / 256, 256, 0, stream>>>(batch, gstart, N, G);
    pool_kernel<<<G, 128, 0, stream>>>(H3, gstart, na, nbonds, mw, pooled, G);
    mlp_kernel<<<G, 128, 0, stream>>>(pooled, fW1, fb1, fW2, fb2, fW3, fb3, fW4, fb4, out, G);
}

// Round 3
// 359.571 us; speedup vs baseline: 1.7788x; 1.0021x over previous
//
#include <hip/hip_runtime.h>
#include <math.h>

// ---------------------------------------------------------------------------
// GCN regressor, round 3:
//   - isq prescaled into features -> agg is a pure gather-sum, unroll 8.
//   - width-128 aggs: 32 lanes/row (2 rows per wave).
//   - MFMA f16 GEMM with fused epilogue (bias/tanh/rowscale) + LDS repack
//     for coalesced 16B stores.
//   - single-kernel decoupled-lookback scan, fused pool+MLP, combined wcast.
// ---------------------------------------------------------------------------

typedef _Float16 v8h __attribute__((ext_vector_type(8)));
typedef _Float16 v4h __attribute__((ext_vector_type(4)));
typedef float    v4f __attribute__((ext_vector_type(4)));

#define GLOAD_LDS16(g, l)                                                      \
    __builtin_amdgcn_global_load_lds(                                          \
        (const __attribute__((address_space(1))) void*)(g),                    \
        (__attribute__((address_space(3))) void*)(l), 16, 0, 0)

// ---------------- CSR build ----------------
__global__ void count_deg_kernel(const int* __restrict__ dst, int* __restrict__ deg, int E) {
    int e = blockIdx.x * blockDim.x + threadIdx.x;
    if (e < E) atomicAdd(&deg[dst[e]], 1);
}

// one-kernel inclusive scan (decoupled lookback via ticket ordering) + rsqrt
__global__ __launch_bounds__(1024) void scan_fused_kernel(const int* __restrict__ deg,
                                                          int* __restrict__ row_start,
                                                          float* __restrict__ isq,
                                                          int* __restrict__ ticket,
                                                          int* __restrict__ pub,
                                                          int n) {
    __shared__ int s[1024];
    __shared__ int sb;
    __shared__ int sprev;
    int t = threadIdx.x;
    if (t == 0) sb = atomicAdd(ticket, 1);
    __syncthreads();
    int b = sb;
    int i = b * 1024 + t;
    int v = (i < n) ? deg[i] : 0;
    if (i < n) isq[i] = rsqrtf((float)(v + 1));   // +1 self-loop
    s[t] = v;
    __syncthreads();
    for (int off = 1; off < 1024; off <<= 1) {
        int x = 0;
        if (t >= off) x = s[t - off];
        __syncthreads();
        s[t] += x;
        __syncthreads();
    }
    if (t == 1023) {
        int prev = 0;
        if (b > 0) {
            int val;
            do { val = atomicAdd(&pub[b - 1], 0); } while (val == 0);
            prev = val - 1;                         // pub stores incl+1 (0 = unset)
        }
        atomicExch(&pub[b], prev + s[1023] + 1);
        sprev = prev;
    }
    __syncthreads();
    if (i < n) row_start[i + 1] = s[t] + sprev;
    if (b == 0 && t == 0) row_start[0] = 0;
}

__global__ void fill_csr_kernel(const int* __restrict__ src, const int* __restrict__ dst,
                                int* __restrict__ cursor, const int* __restrict__ row_start,
                                int* __restrict__ colx, int E) {
    int e = blockIdx.x * blockDim.x + threadIdx.x;
    if (e < E) {
        int d = dst[e];
        int pos = atomicAdd(&cursor[d], 1);
        colx[row_start[d] + pos] = src[e];
    }
}

// ---------------- prescale / casts ----------------
// X16s[r] = (f16)(x[r] * isq[r]) — 4 elems per thread
__global__ void prescale_x_kernel(const float* __restrict__ x, const float* __restrict__ isq,
                                  _Float16* __restrict__ out, int n4) {
    int i = blockIdx.x * blockDim.x + threadIdx.x;
    if (i < n4) {
        float sc = isq[i >> 5];                    // row = (i*4)/128
        float4 v = *(const float4*)(x + (size_t)i * 4);
        v4h o = {(_Float16)(v.x * sc), (_Float16)(v.y * sc),
                 (_Float16)(v.z * sc), (_Float16)(v.w * sc)};
        *(v4h*)(out + (size_t)i * 4) = o;
    }
}

// all three GCN weights cast+transposed in one kernel
__global__ void wcast_all_kernel(const float* __restrict__ W1, _Float16* __restrict__ Wt1,
                                 const float* __restrict__ W2, _Float16* __restrict__ Wt2,
                                 const float* __restrict__ W3, _Float16* __restrict__ Wt3,
                                 int F, int H) {
    int i = blockIdx.x * blockDim.x + threadIdx.x;
    int s1 = F * H, s2 = H * H, s3 = H * F;
    if (i < s1) {
        int k = i / H, n = i % H;
        Wt1[(size_t)n * F + k] = (_Float16)W1[i];
    } else if (i < s1 + s2) {
        int j = i - s1;
        int k = j / H, n = j % H;
        Wt2[(size_t)n * H + k] = (_Float16)W2[j];
    } else if (i < s1 + s2 + s3) {
        int j = i - s1 - s2;
        int k = j / F, n = j % F;
        Wt3[(size_t)n * H + k] = (_Float16)W3[j];
    }
}

// ---------------- aggregation: pure gather-sum of prescaled features --------
// out[r] = f(isq_r * (feat[r] + sum_{s in N(r)} feat[s]))   [+bias][tanh]
// LPR lanes per row (32 or 64), VEC=4 f16 per lane. Row width = LPR*4.
template <int LPR, bool OUTF32, bool DOTANH, bool HASBIAS>
__global__ __launch_bounds__(256) void aggsum_kernel(const _Float16* __restrict__ feat,
                                                     void* __restrict__ outp,
                                                     const int* __restrict__ row_start,
                                                     const int* __restrict__ colx,
                                                     const float* __restrict__ isq,
                                                     const float* __restrict__ bias,
                                                     int n) {
    const int W = LPR * 4;
    const int RPW = 64 / LPR;                       // rows per wave
    int wid = blockIdx.x * 4 + (threadIdx.x >> 6);
    int lane = threadIdx.x & 63;
    int row = wid * RPW + (RPW == 2 ? (lane >> 5) : 0);
    if (row >= n) return;
    int c4 = (lane & (LPR - 1)) * 4;
    const _Float16* fb = feat + c4;

    float a0, a1, a2, a3;
    {
        v4h v = *(const v4h*)(fb + (size_t)row * W);
        a0 = (float)v[0]; a1 = (float)v[1]; a2 = (float)v[2]; a3 = (float)v[3];
    }
    int j = row_start[row], end = row_start[row + 1];
    for (; j + 8 <= end; j += 8) {
        v4h t[8];
#pragma unroll
        for (int u = 0; u < 8; ++u)
            t[u] = *(const v4h*)(fb + (size_t)colx[j + u] * W);
#pragma unroll
        for (int u = 0; u < 8; ++u) {
            a0 += (float)t[u][0]; a1 += (float)t[u][1];
            a2 += (float)t[u][2]; a3 += (float)t[u][3];
        }
    }
    for (; j < end; ++j) {
        v4h v = *(const v4h*)(fb + (size_t)colx[j] * W);
        a0 += (float)v[0]; a1 += (float)v[1]; a2 += (float)v[2]; a3 += (float)v[3];
    }
    float isd = isq[row];
    a0 *= isd; a1 *= isd; a2 *= isd; a3 *= isd;
    if constexpr (HASBIAS) {
        a0 += bias[c4 + 0]; a1 += bias[c4 + 1]; a2 += bias[c4 + 2]; a3 += bias[c4 + 3];
    }
    if constexpr (DOTANH) {
        a0 = tanhf(a0); a1 = tanhf(a1); a2 = tanhf(a2); a3 = tanhf(a3);
    }
    if constexpr (OUTF32) {
        float4 o = {a0, a1, a2, a3};
        *(float4*)((float*)outp + (size_t)row * W + c4) = o;
    } else {
        v4h o = {(_Float16)a0, (_Float16)a1, (_Float16)a2, (_Float16)a3};
        *(v4h*)((_Float16*)outp + (size_t)row * W + c4) = o;
    }
}

// ---------------- MFMA f16 GEMM ----------------
// C[Mpad,Nout] = post(A[Mpad,K] @ Bt[Nout,K]^T), post = (+bias)(tanh)(*rowscale)
// 128x128 tile, BK=64, 256 threads = 4 waves (2x2), each wave 64x64 (4x4 frags).
__global__ __launch_bounds__(256) void gemm16_kernel(const _Float16* __restrict__ A,
                                                     const _Float16* __restrict__ Bt,
                                                     _Float16* __restrict__ C,
                                                     const float* __restrict__ bias,
                                                     const float* __restrict__ rowscale,
                                                     int K, int Nout, int act) {
    __shared__ _Float16 smem[16384];                // 32 KB: As|Bs, reused as Cs
    _Float16* As = smem;
    _Float16* Bs = smem + 8192;
    const int tid = threadIdx.x;
    const int lane = tid & 63;
    const int wid = tid >> 6;
    const int wr = wid >> 1, wc = wid & 1;
    const int row0 = blockIdx.y * 128, col0 = blockIdx.x * 128;

    v4f acc[4][4];
#pragma unroll
    for (int m = 0; m < 4; ++m)
#pragma unroll
        for (int n = 0; n < 4; ++n) acc[m][n] = (v4f){0.f, 0.f, 0.f, 0.f};

    for (int k0 = 0; k0 < K; k0 += 64) {
#pragma unroll
        for (int c = 0; c < 4; ++c) {
            int l = c * 2048 + tid * 8;
            int row = l >> 6, kh = l & 63;
            GLOAD_LDS16(A + (size_t)(row0 + row) * K + k0 + kh, As + l);
        }
#pragma unroll
        for (int c = 0; c < 4; ++c) {
            int l = c * 2048 + tid * 8;
            int cc = l >> 6, kh = l & 63;
            GLOAD_LDS16(Bt + (size_t)(col0 + cc) * K + k0 + kh, Bs + l);
        }
        __syncthreads();
#pragma unroll
        for (int kk = 0; kk < 2; ++kk) {
            v8h af[4], bf[4];
            const int khb = kk * 32 + (lane >> 4) * 8;
#pragma unroll
            for (int m = 0; m < 4; ++m)
                af[m] = *(const v8h*)&As[(wr * 64 + m * 16 + (lane & 15)) * 64 + khb];
#pragma unroll
            for (int n = 0; n < 4; ++n)
                bf[n] = *(const v8h*)&Bs[(wc * 64 + n * 16 + (lane & 15)) * 64 + khb];
#pragma unroll
            for (int m = 0; m < 4; ++m)
#pragma unroll
                for (int n = 0; n < 4; ++n)
                    acc[m][n] = __builtin_amdgcn_mfma_f32_16x16x32_f16(af[m], bf[n], acc[m][n], 0, 0, 0);
        }
        __syncthreads();
    }

    // epilogue -> LDS (f16), then coalesced 16B stores
#pragma unroll
    for (int m = 0; m < 4; ++m) {
#pragma unroll
        for (int n = 0; n < 4; ++n) {
            int lcol = wc * 64 + n * 16 + (lane & 15);
            float bv = bias ? bias[col0 + lcol] : 0.f;
#pragma unroll
            for (int r = 0; r < 4; ++r) {
                int lrow = wr * 64 + m * 16 + (lane >> 4) * 4 + r;
                float v = acc[m][n][r] + bv;
                if (act) v = tanhf(v);
                if (rowscale) v *= rowscale[row0 + lrow];
                smem[lrow * 128 + lcol] = (_Float16)v;
            }
        }
    }
    __syncthreads();
#pragma unroll
    for (int i = 0; i < 8; ++i) {
        int flat = (i * 256 + tid) * 8;
        int lr = flat >> 7, lc = flat & 127;
        *(v8h*)(C + (size_t)(row0 + lr) * Nout + col0 + lc) = *(const v8h*)&smem[flat];
    }
}

// ---------------- fused pool + MLP head ----------------
__global__ __launch_bounds__(128) void poolmlp_kernel(const float* __restrict__ h3,
                                                      const int* __restrict__ batch,
                                                      const float* __restrict__ na,
                                                      const float* __restrict__ nb,
                                                      const float* __restrict__ mw,
                                                      const float* __restrict__ fW1, const float* __restrict__ fb1,
                                                      const float* __restrict__ fW2, const float* __restrict__ fb2,
                                                      const float* __restrict__ fW3, const float* __restrict__ fb3,
                                                      const float* __restrict__ fW4, const float* __restrict__ fb4,
                                                      float* __restrict__ out, int n) {
    __shared__ float p[129];
    __shared__ float o1[128];
    __shared__ float o2[64];
    __shared__ float o3[32];
    __shared__ int sbeg, send;
    int g = blockIdx.x, t = threadIdx.x;
    if (t < 2) {
        int target = g + t;
        int lo = 0, hi = n;
        while (lo < hi) {
            int mid = (lo + hi) >> 1;
            if (batch[mid] < target) lo = mid + 1; else hi = mid;
        }
        if (t == 0) sbeg = lo; else send = lo;
    }
    __syncthreads();
    int beg = sbeg, end = send;
    float s = 0.f;
    for (int i = beg; i < end; ++i) s += h3[(size_t)i * 128 + t];
    float inv = 1.f / fmaxf((float)(end - beg), 1.f);
    p[t] = s * inv;
    if (t == 0)
        p[128] = (end > beg) ? (na[g] + nb[g] + mw[g]) * (1.f / 3.f) : 0.f;
    __syncthreads();
    {
        float a = fb1[t];
        for (int i = 0; i < 129; ++i) a += p[i] * fW1[i * 128 + t];
        o1[t] = fmaxf(a, 0.f);
    }
    __syncthreads();
    if (t < 64) {
        float a = fb2[t];
        for (int i = 0; i < 128; ++i) a += o1[i] * fW2[i * 64 + t];
        o2[t] = fmaxf(a, 0.f);
    }
    __syncthreads();
    if (t < 32) {
        float a = fb3[t];
        for (int i = 0; i < 64; ++i) a += o2[i] * fW3[i * 32 + t];
        o3[t] = fmaxf(a, 0.f);
    }
    __syncthreads();
    if (t == 0) {
        float a = fb4[0];
        for (int i = 0; i < 32; ++i) a += o3[i] * fW4[i];
        out[g] = a;
    }
}

// ---------------------------------------------------------------------------
extern "C" void kernel_launch(void* const* d_in, const int* in_sizes, int n_in,
                              void* d_out, int out_size, void* d_ws, size_t ws_size,
                              hipStream_t stream) {
    const float* x     = (const float*)d_in[0];
    const int*   ei    = (const int*)d_in[1];
    const int*   batch = (const int*)d_in[2];
    const float* na    = (const float*)d_in[3];
    const float* nbonds= (const float*)d_in[4];
    const float* mw    = (const float*)d_in[5];
    const float* W1 = (const float*)d_in[6];  const float* b1 = (const float*)d_in[7];
    const float* W2 = (const float*)d_in[8];  const float* b2 = (const float*)d_in[9];
    const float* W3 = (const float*)d_in[10]; const float* b3 = (const float*)d_in[11];
    const float* fW1 = (const float*)d_in[12]; const float* fb1 = (const float*)d_in[13];
    const float* fW2 = (const float*)d_in[14]; const float* fb2 = (const float*)d_in[15];
    const float* fW3 = (const float*)d_in[16]; const float* fb3 = (const float*)d_in[17];
    const float* fW4 = (const float*)d_in[18]; const float* fb4 = (const float*)d_in[19];
    float* out = (float*)d_out;

    const int N = in_sizes[2];          // 50000
    const int E = in_sizes[1] / 2;      // 800000
    const int F = in_sizes[0] / N;      // 128
    const int H = in_sizes[7];          // 256
    const int G = in_sizes[3];          // 1024
    const int Npad = ((N + 127) / 128) * 128;   // 50048
    const int nb = (N + 1023) / 1024;

    const int* src = ei;
    const int* dst = ei + E;

    // ---- workspace carve-up (deg..sync region is zeroed in one memset) ----
    char* w = (char*)d_ws;
    size_t off = 0;
    auto take = [&](size_t bytes) -> void* {
        void* p = w + off;
        off += (bytes + 255) & ~(size_t)255;
        return p;
    };
    int*      deg       = (int*)take((size_t)N * 4);
    int*      cursor    = (int*)take((size_t)N * 4);
    int*      ticket    = (int*)take(4);
    int*      pub       = (int*)take((size_t)nb * 4);
    size_t zero_bytes = off;
    int*      row_start = (int*)take((size_t)(N + 1) * 4);
    int*      colx      = (int*)take((size_t)E * 4);
    float*    isq       = (float*)take((size_t)Npad * 4);
    _Float16* X16s      = (_Float16*)take((size_t)Npad * F * 2);
    _Float16* A0        = (_Float16*)take((size_t)Npad * F * 2);
    _Float16* H1        = (_Float16*)take((size_t)Npad * H * 2);
    _Float16* T2s       = (_Float16*)take((size_t)Npad * H * 2);
    _Float16* H2        = (_Float16*)take((size_t)Npad * H * 2);
    _Float16* T3s       = (_Float16*)take((size_t)Npad * F * 2);
    float*    H3        = (float*)take((size_t)Npad * F * 4);
    _Float16* Wt1       = (_Float16*)take((size_t)F * H * 2);
    _Float16* Wt2       = (_Float16*)take((size_t)H * H * 2);
    _Float16* Wt3       = (_Float16*)take((size_t)H * F * 2);
    (void)ws_size; (void)n_in; (void)out_size;

    hipMemsetAsync(d_ws, 0, zero_bytes, stream);

    count_deg_kernel<<<(E + 255) / 256, 256, 0, stream>>>(dst, deg, E);
    scan_fused_kernel<<<nb, 1024, 0, stream>>>(deg, row_start, isq, ticket, pub, N);
    fill_csr_kernel<<<(E + 255) / 256, 256, 0, stream>>>(src, dst, cursor, row_start, colx, E);
    prescale_x_kernel<<<((N * F / 4) + 255) / 256, 256, 0, stream>>>(x, isq, X16s, N * F / 4);
    {
        int tot = F * H + H * H + H * F;
        wcast_all_kernel<<<(tot + 255) / 256, 256, 0, stream>>>(W1, Wt1, W2, Wt2, W3, Wt3, F, H);
    }

    const int g128 = (N + 7) / 8;       // LPR=32: 8 rows per block
    const int g256 = (N + 3) / 4;       // LPR=64: 4 rows per block

    // conv1: agg(prescaled x) -> GEMM(+b1, tanh)
    aggsum_kernel<32, false, false, false><<<g128, 256, 0, stream>>>(X16s, A0, row_start, colx, isq, nullptr, N);
    {
        dim3 grid(H / 128, Npad / 128);
        gemm16_kernel<<<grid, 256, 0, stream>>>(A0, Wt1, H1, b1, nullptr, F, H, 1);
    }
    // conv2: GEMM(*isq) -> agg(+b2, tanh)
    {
        dim3 grid(H / 128, Npad / 128);
        gemm16_kernel<<<grid, 256, 0, stream>>>(H1, Wt2, T2s, nullptr, isq, H, H, 0);
    }
    aggsum_kernel<64, false, true, true><<<g256, 256, 0, stream>>>(T2s, H2, row_start, colx, isq, b2, N);
    // conv3: GEMM(*isq) -> agg(+b3), fp32 out
    {
        dim3 grid(F / 128, Npad / 128);
        gemm16_kernel<<<grid, 256, 0, stream>>>(H2, Wt3, T3s, nullptr, isq, H, F, 0);
    }
    aggsum_kernel<32, true, false, true><<<g128, 256, 0, stream>>>(T3s, H3, row_start, colx, isq, b3, N);

    // fused pool + MLP head
    poolmlp_kernel<<<G, 128, 0, stream>>>(H3, batch, na, nbonds, mw,
                                          fW1, fb1, fW2, fb2, fW3, fb3, fW4, fb4, out, N);
}

// Round 4
// 344.974 us; speedup vs baseline: 1.8541x; 1.0423x over previous
//
#include <hip/hip_runtime.h>
#include <math.h>

// ---------------------------------------------------------------------------
// GCN regressor, round 4:
//   - parallel 3-kernel scan restored (lookback chain in round 3 suspected
//     ~50-100us serialization); isq fused into block-scan.
//   - aggregation: 16B (v8h) gathers; 256-wide: 2 rows/wave, 128-wide: 4.
//   - MFMA f16 GEMM with fused epilogue + LDS repack (unchanged).
//   - count_deg + weight-cast merged into one launch.
// ---------------------------------------------------------------------------

typedef _Float16 v8h __attribute__((ext_vector_type(8)));
typedef _Float16 v4h __attribute__((ext_vector_type(4)));
typedef float    v4f __attribute__((ext_vector_type(4)));

#define GLOAD_LDS16(g, l)                                                      \
    __builtin_amdgcn_global_load_lds(                                          \
        (const __attribute__((address_space(1))) void*)(g),                    \
        (__attribute__((address_space(3))) void*)(l), 16, 0, 0)

// ---------------- CSR build ----------------
// blocks [0, nblkE): degree count; blocks [nblkE, ...): weight cast+transpose
__global__ void count_wcast_kernel(const int* __restrict__ dst, int* __restrict__ deg, int E,
                                   int nblkE,
                                   const float* __restrict__ W1, _Float16* __restrict__ Wt1,
                                   const float* __restrict__ W2, _Float16* __restrict__ Wt2,
                                   const float* __restrict__ W3, _Float16* __restrict__ Wt3,
                                   int F, int H) {
    int b = blockIdx.x;
    if (b < nblkE) {
        int e = b * 256 + threadIdx.x;
        if (e < E) atomicAdd(&deg[dst[e]], 1);
    } else {
        int i = (b - nblkE) * 256 + threadIdx.x;
        int s1 = F * H, s2 = H * H, s3 = H * F;
        if (i < s1) {
            int k = i / H, n = i % H;
            Wt1[(size_t)n * F + k] = (_Float16)W1[i];
        } else if (i < s1 + s2) {
            int j = i - s1;
            int k = j / H, n = j % H;
            Wt2[(size_t)n * H + k] = (_Float16)W2[j];
        } else if (i < s1 + s2 + s3) {
            int j = i - s1 - s2;
            int k = j / F, n = j % F;
            Wt3[(size_t)n * H + k] = (_Float16)W3[j];
        }
    }
}

__global__ __launch_bounds__(1024) void scan_block_kernel(const int* __restrict__ deg,
                                                          int* __restrict__ row_start,
                                                          float* __restrict__ isq,
                                                          int* __restrict__ bsum, int n) {
    __shared__ int s[1024];
    int t = threadIdx.x;
    int i = blockIdx.x * 1024 + t;
    int v = (i < n) ? deg[i] : 0;
    if (i < n) isq[i] = rsqrtf((float)(v + 1));   // +1 self-loop
    s[t] = v;
    __syncthreads();
    for (int off = 1; off < 1024; off <<= 1) {
        int x = 0;
        if (t >= off) x = s[t - off];
        __syncthreads();
        s[t] += x;
        __syncthreads();
    }
    if (i < n) row_start[i + 1] = s[t];
    if (t == 1023) bsum[blockIdx.x] = s[1023];
}

__global__ void scan_bsum_kernel(int* __restrict__ bsum, int* __restrict__ row_start, int nb) {
    if (threadIdx.x == 0) {
        row_start[0] = 0;
        int run = 0;
        for (int b = 0; b < nb; ++b) { int t = bsum[b]; bsum[b] = run; run += t; }
    }
}

__global__ void add_offset_kernel(int* __restrict__ row_start, const int* __restrict__ bsum, int n) {
    int i = blockIdx.x * 1024 + threadIdx.x;
    if (i < n) row_start[i + 1] += bsum[blockIdx.x];
}

__global__ void fill_csr_kernel(const int* __restrict__ src, const int* __restrict__ dst,
                                int* __restrict__ cursor, const int* __restrict__ row_start,
                                int* __restrict__ colx, int E) {
    int e = blockIdx.x * blockDim.x + threadIdx.x;
    if (e < E) {
        int d = dst[e];
        int pos = atomicAdd(&cursor[d], 1);
        colx[row_start[d] + pos] = src[e];
    }
}

// ---------------- prescale ----------------
// X16s[r] = (f16)(x[r] * isq[r]) — 4 elems per thread (F=128)
__global__ void prescale_x_kernel(const float* __restrict__ x, const float* __restrict__ isq,
                                  _Float16* __restrict__ out, int n4) {
    int i = blockIdx.x * blockDim.x + threadIdx.x;
    if (i < n4) {
        float sc = isq[i >> 5];
        float4 v = *(const float4*)(x + (size_t)i * 4);
        v4h o = {(_Float16)(v.x * sc), (_Float16)(v.y * sc),
                 (_Float16)(v.z * sc), (_Float16)(v.w * sc)};
        *(v4h*)(out + (size_t)i * 4) = o;
    }
}

// ---------------- aggregation: pure gather-sum of prescaled features --------
// out[r] = f(isq_r * sum_{s in N(r) u {r}} feat[s])   [+bias][tanh]
// LPR lanes per row, each lane owns 8 f16 (16B). Row width = LPR*8.
template <int LPR, bool OUTF32, bool DOTANH, bool HASBIAS>
__global__ __launch_bounds__(256) void aggsum_kernel(const _Float16* __restrict__ feat,
                                                     void* __restrict__ outp,
                                                     const int* __restrict__ row_start,
                                                     const int* __restrict__ colx,
                                                     const float* __restrict__ isq,
                                                     const float* __restrict__ bias,
                                                     int n) {
    const int W = LPR * 8;
    const int RPW = 64 / LPR;                       // rows per wave
    int wid = blockIdx.x * 4 + (threadIdx.x >> 6);
    int lane = threadIdx.x & 63;
    int row = wid * RPW + lane / LPR;
    if (row >= n) return;
    int c8 = (lane & (LPR - 1)) * 8;
    const _Float16* fb = feat + c8;

    float a[8];
    {
        v8h v = *(const v8h*)(fb + (size_t)row * W);
#pragma unroll
        for (int k = 0; k < 8; ++k) a[k] = (float)v[k];
    }
    int j = row_start[row], end = row_start[row + 1];
    for (; j + 8 <= end; j += 8) {
        v8h t[8];
#pragma unroll
        for (int u = 0; u < 8; ++u)
            t[u] = *(const v8h*)(fb + (size_t)colx[j + u] * W);
#pragma unroll
        for (int u = 0; u < 8; ++u)
#pragma unroll
            for (int k = 0; k < 8; ++k) a[k] += (float)t[u][k];
    }
    for (; j < end; ++j) {
        v8h v = *(const v8h*)(fb + (size_t)colx[j] * W);
#pragma unroll
        for (int k = 0; k < 8; ++k) a[k] += (float)v[k];
    }
    float isd = isq[row];
#pragma unroll
    for (int k = 0; k < 8; ++k) a[k] *= isd;
    if constexpr (HASBIAS) {
        float4 b0 = *(const float4*)(bias + c8);
        float4 b1 = *(const float4*)(bias + c8 + 4);
        a[0] += b0.x; a[1] += b0.y; a[2] += b0.z; a[3] += b0.w;
        a[4] += b1.x; a[5] += b1.y; a[6] += b1.z; a[7] += b1.w;
    }
    if constexpr (DOTANH) {
#pragma unroll
        for (int k = 0; k < 8; ++k) a[k] = tanhf(a[k]);
    }
    if constexpr (OUTF32) {
        float* o = (float*)outp + (size_t)row * W + c8;
        float4 o0 = {a[0], a[1], a[2], a[3]};
        float4 o1 = {a[4], a[5], a[6], a[7]};
        *(float4*)o = o0;
        *(float4*)(o + 4) = o1;
    } else {
        v8h o;
#pragma unroll
        for (int k = 0; k < 8; ++k) o[k] = (_Float16)a[k];
        *(v8h*)((_Float16*)outp + (size_t)row * W + c8) = o;
    }
}

// ---------------- MFMA f16 GEMM ----------------
// C[Mpad,Nout] = post(A[Mpad,K] @ Bt[Nout,K]^T), post = (+bias)(tanh)(*rowscale)
// 128x128 tile, BK=64, 256 threads = 4 waves (2x2), each wave 64x64 (4x4 frags).
__global__ __launch_bounds__(256) void gemm16_kernel(const _Float16* __restrict__ A,
                                                     const _Float16* __restrict__ Bt,
                                                     _Float16* __restrict__ C,
                                                     const float* __restrict__ bias,
                                                     const float* __restrict__ rowscale,
                                                     int K, int Nout, int act) {
    __shared__ _Float16 smem[16384];                // 32 KB: As|Bs, reused as Cs
    _Float16* As = smem;
    _Float16* Bs = smem + 8192;
    const int tid = threadIdx.x;
    const int lane = tid & 63;
    const int wid = tid >> 6;
    const int wr = wid >> 1, wc = wid & 1;
    const int row0 = blockIdx.y * 128, col0 = blockIdx.x * 128;

    v4f acc[4][4];
#pragma unroll
    for (int m = 0; m < 4; ++m)
#pragma unroll
        for (int n = 0; n < 4; ++n) acc[m][n] = (v4f){0.f, 0.f, 0.f, 0.f};

    for (int k0 = 0; k0 < K; k0 += 64) {
#pragma unroll
        for (int c = 0; c < 4; ++c) {
            int l = c * 2048 + tid * 8;
            int row = l >> 6, kh = l & 63;
            GLOAD_LDS16(A + (size_t)(row0 + row) * K + k0 + kh, As + l);
        }
#pragma unroll
        for (int c = 0; c < 4; ++c) {
            int l = c * 2048 + tid * 8;
            int cc = l >> 6, kh = l & 63;
            GLOAD_LDS16(Bt + (size_t)(col0 + cc) * K + k0 + kh, Bs + l);
        }
        __syncthreads();
#pragma unroll
        for (int kk = 0; kk < 2; ++kk) {
            v8h af[4], bf[4];
            const int khb = kk * 32 + (lane >> 4) * 8;
#pragma unroll
            for (int m = 0; m < 4; ++m)
                af[m] = *(const v8h*)&As[(wr * 64 + m * 16 + (lane & 15)) * 64 + khb];
#pragma unroll
            for (int n = 0; n < 4; ++n)
                bf[n] = *(const v8h*)&Bs[(wc * 64 + n * 16 + (lane & 15)) * 64 + khb];
#pragma unroll
            for (int m = 0; m < 4; ++m)
#pragma unroll
                for (int n = 0; n < 4; ++n)
                    acc[m][n] = __builtin_amdgcn_mfma_f32_16x16x32_f16(af[m], bf[n], acc[m][n], 0, 0, 0);
        }
        __syncthreads();
    }

    // epilogue -> LDS (f16), then coalesced 16B stores
#pragma unroll
    for (int m = 0; m < 4; ++m) {
#pragma unroll
        for (int n = 0; n < 4; ++n) {
            int lcol = wc * 64 + n * 16 + (lane & 15);
            float bv = bias ? bias[col0 + lcol] : 0.f;
#pragma unroll
            for (int r = 0; r < 4; ++r) {
                int lrow = wr * 64 + m * 16 + (lane >> 4) * 4 + r;
                float v = acc[m][n][r] + bv;
                if (act) v = tanhf(v);
                if (rowscale) v *= rowscale[row0 + lrow];
                smem[lrow * 128 + lcol] = (_Float16)v;
            }
        }
    }
    __syncthreads();
#pragma unroll
    for (int i = 0; i < 8; ++i) {
        int flat = (i * 256 + tid) * 8;
        int lr = flat >> 7, lc = flat & 127;
        *(v8h*)(C + (size_t)(row0 + lr) * Nout + col0 + lc) = *(const v8h*)&smem[flat];
    }
}

// ---------------- fused pool + MLP head ----------------
__global__ __launch_bounds__(128) void poolmlp_kernel(const float* __restrict__ h3,
                                                      const int* __restrict__ batch,
                                                      const float* __restrict__ na,
                                                      const float* __restrict__ nb,
                                                      const float* __restrict__ mw,
                                                      const float* __restrict__ fW1, const float* __restrict__ fb1,
                                                      const float* __restrict__ fW2, const float* __restrict__ fb2,
                                                      const float* __restrict__ fW3, const float* __restrict__ fb3,
                                                      const float* __restrict__ fW4, const float* __restrict__ fb4,
                                                      float* __restrict__ out, int n) {
    __shared__ float p[129];
    __shared__ float o1[128];
    __shared__ float o2[64];
    __shared__ float o3[32];
    __shared__ int sbeg, send;
    int g = blockIdx.x, t = threadIdx.x;
    if (t < 2) {
        int target = g + t;
        int lo = 0, hi = n;
        while (lo < hi) {
            int mid = (lo + hi) >> 1;
            if (batch[mid] < target) lo = mid + 1; else hi = mid;
        }
        if (t == 0) sbeg = lo; else send = lo;
    }
    __syncthreads();
    int beg = sbeg, end = send;
    float s = 0.f;
    for (int i = beg; i < end; ++i) s += h3[(size_t)i * 128 + t];
    float inv = 1.f / fmaxf((float)(end - beg), 1.f);
    p[t] = s * inv;
    if (t == 0)
        p[128] = (end > beg) ? (na[g] + nb[g] + mw[g]) * (1.f / 3.f) : 0.f;
    __syncthreads();
    {
        float a = fb1[t];
        for (int i = 0; i < 129; ++i) a += p[i] * fW1[i * 128 + t];
        o1[t] = fmaxf(a, 0.f);
    }
    __syncthreads();
    if (t < 64) {
        float a = fb2[t];
        for (int i = 0; i < 128; ++i) a += o1[i] * fW2[i * 64 + t];
        o2[t] = fmaxf(a, 0.f);
    }
    __syncthreads();
    if (t < 32) {
        float a = fb3[t];
        for (int i = 0; i < 64; ++i) a += o2[i] * fW3[i * 32 + t];
        o3[t] = fmaxf(a, 0.f);
    }
    __syncthreads();
    if (t == 0) {
        float a = fb4[0];
        for (int i = 0; i < 32; ++i) a += o3[i] * fW4[i];
        out[g] = a;
    }
}

// ---------------------------------------------------------------------------
extern "C" void kernel_launch(void* const* d_in, const int* in_sizes, int n_in,
                              void* d_out, int out_size, void* d_ws, size_t ws_size,
                              hipStream_t stream) {
    const float* x     = (const float*)d_in[0];
    const int*   ei    = (const int*)d_in[1];
    const int*   batch = (const int*)d_in[2];
    const float* na    = (const float*)d_in[3];
    const float* nbonds= (const float*)d_in[4];
    const float* mw    = (const float*)d_in[5];
    const float* W1 = (const float*)d_in[6];  const float* b1 = (const float*)d_in[7];
    const float* W2 = (const float*)d_in[8];  const float* b2 = (const float*)d_in[9];
    const float* W3 = (const float*)d_in[10]; const float* b3 = (const float*)d_in[11];
    const float* fW1 = (const float*)d_in[12]; const float* fb1 = (const float*)d_in[13];
    const float* fW2 = (const float*)d_in[14]; const float* fb2 = (const float*)d_in[15];
    const float* fW3 = (const float*)d_in[16]; const float* fb3 = (const float*)d_in[17];
    const float* fW4 = (const float*)d_in[18]; const float* fb4 = (const float*)d_in[19];
    float* out = (float*)d_out;

    const int N = in_sizes[2];          // 50000
    const int E = in_sizes[1] / 2;      // 800000
    const int F = in_sizes[0] / N;      // 128
    const int H = in_sizes[7];          // 256
    const int G = in_sizes[3];          // 1024
    const int Npad = ((N + 127) / 128) * 128;   // 50048
    const int nb = (N + 1023) / 1024;

    const int* src = ei;
    const int* dst = ei + E;

    // ---- workspace carve-up (deg+cursor zeroed in one memset) ----
    char* w = (char*)d_ws;
    size_t off = 0;
    auto take = [&](size_t bytes) -> void* {
        void* p = w + off;
        off += (bytes + 255) & ~(size_t)255;
        return p;
    };
    int*      deg       = (int*)take((size_t)N * 4);
    int*      cursor    = (int*)take((size_t)N * 4);
    size_t zero_bytes = off;
    int*      bsum      = (int*)take(256 * 4);
    int*      row_start = (int*)take((size_t)(N + 1) * 4);
    int*      colx      = (int*)take((size_t)E * 4);
    float*    isq       = (float*)take((size_t)Npad * 4);
    _Float16* X16s      = (_Float16*)take((size_t)Npad * F * 2);
    _Float16* A0        = (_Float16*)take((size_t)Npad * F * 2);
    _Float16* H1        = (_Float16*)take((size_t)Npad * H * 2);
    _Float16* T2s       = (_Float16*)take((size_t)Npad * H * 2);
    _Float16* H2        = (_Float16*)take((size_t)Npad * H * 2);
    _Float16* T3s       = (_Float16*)take((size_t)Npad * F * 2);
    float*    H3        = (float*)take((size_t)Npad * F * 4);
    _Float16* Wt1       = (_Float16*)take((size_t)F * H * 2);
    _Float16* Wt2       = (_Float16*)take((size_t)H * H * 2);
    _Float16* Wt3       = (_Float16*)take((size_t)H * F * 2);
    (void)ws_size; (void)n_in; (void)out_size;

    hipMemsetAsync(d_ws, 0, zero_bytes, stream);

    const int nblkE = (E + 255) / 256;
    const int nblkW = (F * H + H * H + H * F + 255) / 256;
    count_wcast_kernel<<<nblkE + nblkW, 256, 0, stream>>>(dst, deg, E, nblkE,
                                                          W1, Wt1, W2, Wt2, W3, Wt3, F, H);
    scan_block_kernel<<<nb, 1024, 0, stream>>>(deg, row_start, isq, bsum, N);
    scan_bsum_kernel<<<1, 64, 0, stream>>>(bsum, row_start, nb);
    add_offset_kernel<<<nb, 1024, 0, stream>>>(row_start, bsum, N);
    fill_csr_kernel<<<nblkE, 256, 0, stream>>>(src, dst, cursor, row_start, colx, E);
    prescale_x_kernel<<<((N * F / 4) + 255) / 256, 256, 0, stream>>>(x, isq, X16s, N * F / 4);

    const int g128 = (N + 15) / 16;     // LPR=16: 16 rows per block
    const int g256 = (N + 7) / 8;       // LPR=32: 8 rows per block

    // conv1: agg(prescaled x, W=128) -> GEMM(+b1, tanh)
    aggsum_kernel<16, false, false, false><<<g128, 256, 0, stream>>>(X16s, A0, row_start, colx, isq, nullptr, N);
    {
        dim3 grid(H / 128, Npad / 128);
        gemm16_kernel<<<grid, 256, 0, stream>>>(A0, Wt1, H1, b1, nullptr, F, H, 1);
    }
    // conv2: GEMM(*isq) -> agg(W=256, +b2, tanh)
    {
        dim3 grid(H / 128, Npad / 128);
        gemm16_kernel<<<grid, 256, 0, stream>>>(H1, Wt2, T2s, nullptr, isq, H, H, 0);
    }
    aggsum_kernel<32, false, true, true><<<g256, 256, 0, stream>>>(T2s, H2, row_start, colx, isq, b2, N);
    // conv3: GEMM(*isq) -> agg(W=128, +b3), fp32 out
    {
        dim3 grid(F / 128, Npad / 128);
        gemm16_kernel<<<grid, 256, 0, stream>>>(H2, Wt3, T3s, nullptr, isq, H, F, 0);
    }
    aggsum_kernel<16, true, false, true><<<g128, 256, 0, stream>>>(T3s, H3, row_start, colx, isq, b3, N);

    // fused pool + MLP head
    poolmlp_kernel<<<G, 128, 0, stream>>>(H3, batch, na, nbonds, mw,
                                          fW1, fb1, fW2, fb2, fW3, fb3, fW4, fb4, out, N);
}